// Round 2
// baseline (223.452 us; speedup 1.0000x reference)
//
#include <hip/hip_runtime.h>
#include <stdint.h>

#define B_DIM 8
#define N_DIM 2048
#define F_DIM 128
#define D_DIM 128
#define LN_EPS 1e-5f

typedef __attribute__((ext_vector_type(8))) short short8;
typedef __attribute__((ext_vector_type(4))) float floatx4;

__device__ __forceinline__ ushort f2bf(float f) {
    union { float f; uint32_t u; } c;
    c.f = f;
    uint32_t u = c.u;
    return (ushort)((u + 0x7FFFu + ((u >> 16) & 1u)) >> 16);  // RNE
}

__device__ __forceinline__ float bf2f(ushort u) {
    union { uint32_t u; float f; } c;
    c.u = ((uint32_t)u) << 16;
    return c.f;
}

__device__ __forceinline__ void load_lds16(const ushort* g, ushort* l) {
    __builtin_amdgcn_global_load_lds(
        (const __attribute__((address_space(1))) void*)g,
        (__attribute__((address_space(3))) void*)l,
        16, 0, 0);
}

// ---------------------------------------------------------------------------
// Kernel 1: X (B, K=2048, F=128) fp32  ->  Xt (B, F=128, K=2048) bf16.
// 64x64 tile in LDS (stride 65 kills bank conflicts), cvt on load.
// ---------------------------------------------------------------------------
__global__ __launch_bounds__(256) void k_transpose(const float* __restrict__ X,
                                                   ushort* __restrict__ Xt) {
    __shared__ ushort tile[64 * 65];
    const int t = threadIdx.x;
    const int b = blockIdx.z;
    const int k0 = blockIdx.x * 64;   // 32 tiles along K
    const int f0 = blockIdx.y * 64;   // 2 tiles along F

#pragma unroll
    for (int p = 0; p < 2; ++p) {
        int idx = p * 256 + t;
        int kk = idx >> 3;          // 0..63
        int ff = (idx & 7) * 8;     // 0..56
        const float* src = X + (((size_t)b * N_DIM) + k0 + kk) * F_DIM + f0 + ff;
        float4 v0 = *(const float4*)(src);
        float4 v1 = *(const float4*)(src + 4);
        ushort* d = tile + kk * 65 + ff;
        d[0] = f2bf(v0.x); d[1] = f2bf(v0.y); d[2] = f2bf(v0.z); d[3] = f2bf(v0.w);
        d[4] = f2bf(v1.x); d[5] = f2bf(v1.y); d[6] = f2bf(v1.z); d[7] = f2bf(v1.w);
    }
    __syncthreads();

    union U { uint4 v; ushort s[8]; };
#pragma unroll
    for (int p = 0; p < 2; ++p) {
        int idx = p * 256 + t;
        int f2 = idx >> 3;          // 0..63
        int kk2 = (idx & 7) * 8;    // 0..56
        U u;
#pragma unroll
        for (int j = 0; j < 8; ++j) u.s[j] = tile[(kk2 + j) * 65 + f2];
        *(uint4*)(Xt + (((size_t)b * F_DIM) + f0 + f2) * N_DIM + k0 + kk2) = u.v;
    }
}

// ---------------------------------------------------------------------------
// Kernel 2: H[b] = A[b] (2048x2048 fp32) @ X[b] (2048x128), bf16 MFMA,
// fp32 acc, H stored bf16. BM=32, BN=128 (full F: A read exactly once),
// BK=64. 256 thr = 4 waves; wave w owns cols w*32..+32 (2x2 16x16x32 frags).
// A: fp32 global load + cvt + ds_write_b128 (XOR-8 chunk swizzle).
// B: global_load_lds 16B from bf16 Xt. Grid 512 = 2 blocks/CU.
// ---------------------------------------------------------------------------
#define BK 64
__global__ __launch_bounds__(256) void k_gemm(const float* __restrict__ A,
                                              const ushort* __restrict__ Xt,
                                              ushort* __restrict__ H) {
    __shared__ __align__(16) ushort As[32 * BK];    // 4 KB, chunk-swizzled
    __shared__ __align__(16) ushort Bs[128 * BK];   // 16 KB, chunk-swizzled
    const int t = threadIdx.x;
    const int lane = t & 63;
    const int w = t >> 6;            // wave 0..3
    const int q = lane >> 4;         // 0..3
    const int mr = lane & 15;        // 0..15
    const int bb = blockIdx.y;
    const int m0 = blockIdx.x * 32;

    const float* Ab = A + ((size_t)bb * N_DIM + m0) * N_DIM;
    const ushort* Xb = Xt + (size_t)bb * F_DIM * N_DIM;

    floatx4 acc[2][2];
#pragma unroll
    for (int i = 0; i < 2; ++i)
#pragma unroll
        for (int j = 0; j < 2; ++j) acc[i][j] = (floatx4){0.f, 0.f, 0.f, 0.f};

    // A staging: thread t -> row am (0..31), 8-float k-chunk akc (0..7)
    const int am = t >> 3;
    const int akc = t & 7;
    const float* a_src = Ab + (size_t)am * N_DIM + akc * 8;
    ushort* a_dst = As + ((am * 8) + (akc ^ (am & 7))) * 8;  // swizzled chunk

    // B staging: 4 chunks/thread via global_load_lds
    const ushort* b_src[4];
    ushort* b_dst[4];
#pragma unroll
    for (int p = 0; p < 4; ++p) {
        int c = p * 256 + t;
        int n = c >> 3;                          // 0..127
        int kl = (c & 7) ^ (n & 7);
        b_src[p] = Xb + (size_t)n * N_DIM + kl * 8;
        b_dst[p] = Bs + c * 8;
    }

    for (int k0 = 0; k0 < N_DIM; k0 += BK) {
#pragma unroll
        for (int p = 0; p < 4; ++p) load_lds16(b_src[p] + k0, b_dst[p]);

        float4 v0 = *(const float4*)(a_src + k0);
        float4 v1 = *(const float4*)(a_src + k0 + 4);
        short8 ap;
        ap[0] = (short)f2bf(v0.x); ap[1] = (short)f2bf(v0.y);
        ap[2] = (short)f2bf(v0.z); ap[3] = (short)f2bf(v0.w);
        ap[4] = (short)f2bf(v1.x); ap[5] = (short)f2bf(v1.y);
        ap[6] = (short)f2bf(v1.z); ap[7] = (short)f2bf(v1.w);
        *(short8*)a_dst = ap;
        __syncthreads();

#pragma unroll
        for (int ks = 0; ks < 2; ++ks) {
            short8 af[2], bf[2];
#pragma unroll
            for (int i = 0; i < 2; ++i) {
                int m = mr + i * 16;
                int chunk = m * 8 + ((ks * 4 + q) ^ (m & 7));
                af[i] = *(const short8*)(As + chunk * 8);
            }
#pragma unroll
            for (int j = 0; j < 2; ++j) {
                int n = w * 32 + j * 16 + mr;
                int chunk = n * 8 + ((ks * 4 + q) ^ (n & 7));
                bf[j] = *(const short8*)(Bs + chunk * 8);
            }
#pragma unroll
            for (int i = 0; i < 2; ++i)
#pragma unroll
                for (int j = 0; j < 2; ++j)
                    acc[i][j] = __builtin_amdgcn_mfma_f32_16x16x32_bf16(
                        af[i], bf[j], acc[i][j], 0, 0, 0);
        }
        __syncthreads();
    }

    // C/D layout: col = lane&15, row = (lane>>4)*4 + reg  [m89-verified]
#pragma unroll
    for (int i = 0; i < 2; ++i)
#pragma unroll
        for (int j = 0; j < 2; ++j)
#pragma unroll
            for (int r = 0; r < 4; ++r) {
                int grow = m0 + i * 16 + q * 4 + r;
                int gcol = w * 32 + j * 16 + mr;
                H[((size_t)bb * N_DIM + grow) * F_DIM + gcol] = f2bf(acc[i][j][r]);
            }
}

// ---------------------------------------------------------------------------
// Kernel 3: per 32 rows: Y = H_rows @ W^T + b (fp32 W cvt to bf16),
// LayerNorm over D=128, ReLU, fp32 output.
// ---------------------------------------------------------------------------
__global__ __launch_bounds__(256) void k_linear_ln(const ushort* __restrict__ H,
                                                   const float* __restrict__ W,
                                                   const float* __restrict__ bias,
                                                   const float* __restrict__ gamma,
                                                   const float* __restrict__ beta,
                                                   float* __restrict__ out) {
    __shared__ __align__(16) ushort Ws[128 * 136];  // 34 KB padded
    __shared__ __align__(16) ushort Hs[32 * 136];   // 8.5 KB padded
    __shared__ __align__(16) float Yt[32][132];     // 16.5 KB padded

    const int t = threadIdx.x;
    const int lane = t & 63;
    const int w = t >> 6;
    const int q = lane >> 4;
    const int mr = lane & 15;
    const size_t r0 = (size_t)blockIdx.x * 32;

    // stage W (fp32 -> bf16): 2048 8-elem chunks
#pragma unroll
    for (int p = 0; p < 8; ++p) {
        int c = p * 256 + t;
        int d = c >> 4;
        int ff = (c & 15) * 8;
        const float* src = W + d * 128 + ff;
        float4 v0 = *(const float4*)(src);
        float4 v1 = *(const float4*)(src + 4);
        short8 pk;
        pk[0] = (short)f2bf(v0.x); pk[1] = (short)f2bf(v0.y);
        pk[2] = (short)f2bf(v0.z); pk[3] = (short)f2bf(v0.w);
        pk[4] = (short)f2bf(v1.x); pk[5] = (short)f2bf(v1.y);
        pk[6] = (short)f2bf(v1.z); pk[7] = (short)f2bf(v1.w);
        *(short8*)(Ws + d * 136 + ff) = pk;
    }
    // stage H tile (bf16 copy): 512 8-elem chunks
#pragma unroll
    for (int p = 0; p < 2; ++p) {
        int c = p * 256 + t;
        int m = c >> 4;
        int ff = (c & 15) * 8;
        uint4 v = *(const uint4*)(H + (r0 + m) * 128 + ff);
        *(uint4*)(Hs + m * 136 + ff) = v;
    }
    __syncthreads();

    floatx4 acc[2][2];
#pragma unroll
    for (int i = 0; i < 2; ++i)
#pragma unroll
        for (int j = 0; j < 2; ++j) acc[i][j] = (floatx4){0.f, 0.f, 0.f, 0.f};

#pragma unroll
    for (int ks = 0; ks < 4; ++ks) {
        short8 a0 = *(const short8*)(Hs + mr * 136 + ks * 32 + q * 8);
        short8 a1 = *(const short8*)(Hs + (mr + 16) * 136 + ks * 32 + q * 8);
        short8 b0 = *(const short8*)(Ws + (w * 32 + mr) * 136 + ks * 32 + q * 8);
        short8 b1 = *(const short8*)(Ws + (w * 32 + 16 + mr) * 136 + ks * 32 + q * 8);
        acc[0][0] = __builtin_amdgcn_mfma_f32_16x16x32_bf16(a0, b0, acc[0][0], 0, 0, 0);
        acc[0][1] = __builtin_amdgcn_mfma_f32_16x16x32_bf16(a0, b1, acc[0][1], 0, 0, 0);
        acc[1][0] = __builtin_amdgcn_mfma_f32_16x16x32_bf16(a1, b0, acc[1][0], 0, 0, 0);
        acc[1][1] = __builtin_amdgcn_mfma_f32_16x16x32_bf16(a1, b1, acc[1][1], 0, 0, 0);
    }

    // bias add, scatter Y (fp32) into LDS for row-major LN access
    float bv[2] = { bias[w * 32 + mr], bias[w * 32 + 16 + mr] };
#pragma unroll
    for (int i = 0; i < 2; ++i)
#pragma unroll
        for (int j = 0; j < 2; ++j)
#pragma unroll
            for (int r = 0; r < 4; ++r)
                Yt[i * 16 + q * 4 + r][w * 32 + j * 16 + mr] = acc[i][j][r] + bv[j];
    __syncthreads();

    // LayerNorm + ReLU: 8 lanes per row, 16 values each
    const int row = t >> 3;
    const int seg = t & 7;
    float v[16];
    float s = 0.f, s2 = 0.f;
#pragma unroll
    for (int u = 0; u < 16; ++u) {
        v[u] = Yt[row][seg * 16 + u];
        s += v[u];
        s2 += v[u] * v[u];
    }
    s  += __shfl_xor(s, 1);  s2 += __shfl_xor(s2, 1);
    s  += __shfl_xor(s, 2);  s2 += __shfl_xor(s2, 2);
    s  += __shfl_xor(s, 4);  s2 += __shfl_xor(s2, 4);
    float mu = s * (1.0f / 128.0f);
    float var = s2 * (1.0f / 128.0f) - mu * mu;
    float rs = rsqrtf(var + LN_EPS);

    float4 ov[4];
    float* ovf = (float*)ov;
#pragma unroll
    for (int u = 0; u < 16; ++u) {
        int d = seg * 16 + u;
        float y = (v[u] - mu) * rs * gamma[d] + beta[d];
        ovf[u] = fmaxf(y, 0.0f);
    }
    float4* dst = (float4*)(out + (r0 + row) * 128 + seg * 16);
    dst[0] = ov[0]; dst[1] = ov[1]; dst[2] = ov[2]; dst[3] = ov[3];
}

// ---------------------------------------------------------------------------
extern "C" void kernel_launch(void* const* d_in, const int* in_sizes, int n_in,
                              void* d_out, int out_size, void* d_ws, size_t ws_size,
                              hipStream_t stream) {
    const float* A     = (const float*)d_in[0];  // A_hat (8,2048,2048) fp32
    const float* X     = (const float*)d_in[1];  // X (8,2048,128) fp32
    const float* W     = (const float*)d_in[2];  // W (128,128) fp32
    const float* bias  = (const float*)d_in[3];  // b (128) fp32
    const float* gamma = (const float*)d_in[4];  // gamma (128) fp32
    const float* beta  = (const float*)d_in[5];  // beta (128) fp32
    float* out = (float*)d_out;

    ushort* Xt = (ushort*)d_ws;                                   // 4 MB bf16
    ushort* H  = Xt + (size_t)B_DIM * F_DIM * N_DIM;              // 4 MB bf16

    k_transpose<<<dim3(32, 2, 8), 256, 0, stream>>>(X, Xt);
    k_gemm<<<dim3(64, 8), 256, 0, stream>>>(A, Xt, H);
    k_linear_ln<<<dim3(512), 256, 0, stream>>>(H, W, bias, gamma, beta, out);
}